// Round 5
// baseline (382.888 us; speedup 1.0000x reference)
//
#include <hip/hip_runtime.h>
#include <math.h>

#define NBATCH 32
#define NCH 16
#define HW 65536
#define TPB 256

// ws float layout
#define WS_INV_S  0                   // [b][px] signed inv norms, 2097152 floats
#define WS_INV_T  2097152
#define WS_SMALL  4194304
#define WS_SUMS_S (WS_SMALL)          // [b*32+i]: i<16 totals, i>=16 class-1 sums
#define WS_SUMS_T (WS_SMALL + 1024)
#define WS_N1     (WS_SMALL + 2048)   // 8 slots per batch (256)
#define WS_LOSS   (WS_SMALL + 2304)   // 8 slots per batch (256)
#define WS_MEANS  (WS_SMALL + 2560)   // [b*68]: 64 means + 4 recip mean-norms
#define WS_SMALL_FLOATS (2560 + 32 * 68)

__device__ __forceinline__ float wave_sum(float v) {
#pragma unroll
  for (int off = 32; off > 0; off >>= 1) v += __shfl_down(v, off, 64);
  return v;
}

// grid (HW/(TPB*4)=64, NBATCH, 2). z=0->S, z=1->T. Barrier-free streaming.
__global__ __launch_bounds__(TPB) void k_inv(const float* __restrict__ S,
                                             const float* __restrict__ T,
                                             const int* __restrict__ tgt,
                                             float* __restrict__ ws) {
  const int b = blockIdx.y, which = blockIdx.z;
  const int tid = threadIdx.x;
  const int px = blockIdx.x * (TPB * 4) + tid * 4;

  const float* __restrict__ Xb = (which ? T : S) + (size_t)b * NCH * HW;
  float* __restrict__ invb = ws + (which ? WS_INV_T : WS_INV_S) + (size_t)b * HW;

  // transient batch of 16 strided float4 loads — no persistent state
  float4 xv[NCH];
#pragma unroll
  for (int c = 0; c < NCH; ++c) xv[c] = *(const float4*)(Xb + (size_t)c * HW + px);
  const int4 tv = *(const int4*)(tgt + (size_t)b * HW + px);

  float4 ss = {0.f, 0.f, 0.f, 0.f};
#pragma unroll
  for (int c = 0; c < NCH; ++c) {
    ss.x = fmaf(xv[c].x, xv[c].x, ss.x);
    ss.y = fmaf(xv[c].y, xv[c].y, ss.y);
    ss.z = fmaf(xv[c].z, xv[c].z, ss.z);
    ss.w = fmaf(xv[c].w, xv[c].w, ss.w);
  }
  float4 iv;
  iv.x = 1.f / fmaxf(sqrtf(ss.x), 1e-12f);
  iv.y = 1.f / fmaxf(sqrtf(ss.y), 1e-12f);
  iv.z = 1.f / fmaxf(sqrtf(ss.z), 1e-12f);
  iv.w = 1.f / fmaxf(sqrtf(ss.w), 1e-12f);
  // sign-encode class: negative <=> tgt==1
  if (tv.x == 1) iv.x = -iv.x;
  if (tv.y == 1) iv.y = -iv.y;
  if (tv.z == 1) iv.z = -iv.z;
  if (tv.w == 1) iv.w = -iv.w;
  *(float4*)(invb + px) = iv;

  if (which == 0) {  // class-1 count (wave-level, no barrier)
    float n1 = ((tv.x == 1) ? 1.f : 0.f) + ((tv.y == 1) ? 1.f : 0.f) +
               ((tv.z == 1) ? 1.f : 0.f) + ((tv.w == 1) ? 1.f : 0.f);
    n1 = wave_sum(n1);
    if ((tid & 63) == 0) atomicAdd(ws + WS_N1 + b * 8 + (blockIdx.x & 7), n1);
  }
}

// grid (16, NBATCH, 2): block owns 4096 px; channel-contiguous reduction.
__global__ __launch_bounds__(TPB) void k_acc(const float* __restrict__ S,
                                             const float* __restrict__ T,
                                             float* __restrict__ ws) {
  const int b = blockIdx.y, which = blockIdx.z;
  const int tid = threadIdx.x;
  const int pxbase = blockIdx.x * 4096;

  const float* __restrict__ Xb = (which ? T : S) + (size_t)b * NCH * HW;
  const float* __restrict__ invb =
      ws + (which ? WS_INV_T : WS_INV_S) + (size_t)b * HW;
  float* __restrict__ dst = ws + (which ? WS_SUMS_T : WS_SUMS_S) + b * 32;

  // preload |inv| and min(inv,0) for this thread's 16 px (4 float4 iters)
  float4 aiv[4], niv[4];
#pragma unroll
  for (int it = 0; it < 4; ++it) {
    const float4 v = *(const float4*)(invb + pxbase + it * 1024 + tid * 4);
    aiv[it].x = fabsf(v.x); aiv[it].y = fabsf(v.y);
    aiv[it].z = fabsf(v.z); aiv[it].w = fabsf(v.w);
    niv[it].x = fminf(v.x, 0.f); niv[it].y = fminf(v.y, 0.f);
    niv[it].z = fminf(v.z, 0.f); niv[it].w = fminf(v.w, 0.f);
  }

  for (int ch = 0; ch < NCH; ++ch) {
    float tot = 0.f, c1n = 0.f;
#pragma unroll
    for (int it = 0; it < 4; ++it) {
      const float4 x = *(const float4*)(Xb + (size_t)ch * HW + pxbase + it * 1024 + tid * 4);
      tot = fmaf(x.x, aiv[it].x, fmaf(x.y, aiv[it].y,
            fmaf(x.z, aiv[it].z, fmaf(x.w, aiv[it].w, tot))));
      c1n = fmaf(x.x, niv[it].x, fmaf(x.y, niv[it].y,
            fmaf(x.z, niv[it].z, fmaf(x.w, niv[it].w, c1n))));
    }
    tot = wave_sum(tot);
    c1n = wave_sum(c1n);
    if ((tid & 63) == 0) {
      atomicAdd(dst + ch, tot);        // channel total of feat
      atomicAdd(dst + 16 + ch, -c1n);  // class-1 sum (sign-decoded)
    }
  }
}

// grid (NBATCH), 64 threads: means, and reciprocal mean-norms
__global__ void k_prep(float* __restrict__ ws) {
  __shared__ float sm[64];
  const int b = blockIdx.x, tid = threadIdx.x;
  const int tt = tid >> 5, cls = (tid >> 4) & 1, ch = tid & 15;
  float n1v = 0.f;
#pragma unroll
  for (int i = 0; i < 8; ++i) n1v += ws[WS_N1 + b * 8 + i];
  const float cnt = (cls ? n1v : ((float)HW - n1v)) + 1e-6f;
  const float* src = ws + (tt ? WS_SUMS_T : WS_SUMS_S) + b * 32;
  const float s = cls ? src[16 + ch] : (src[ch] - src[16 + ch]);
  const float m = s / cnt;
  sm[tid] = m;
  ws[WS_MEANS + b * 68 + tid] = m;
  __syncthreads();
  if (tid < 4) {  // tid = tt*2+cls over S0,S1,T0,T1
    float ssn = 0.f;
#pragma unroll
    for (int c = 0; c < NCH; ++c) {
      const float v = sm[tid * 16 + c];
      ssn = fmaf(v, v, ssn);
    }
    ws[WS_MEANS + b * 68 + 64 + tid] = 1.f / fmaxf(sqrtf(ssn), 1e-8f);
  }
}

// grid (64, NBATCH). Barrier-free; pc = exp((d0*rn0 - d1*rn1) * signed_inv).
__global__ __launch_bounds__(TPB) void k_pass2(const float* __restrict__ S,
                                               const float* __restrict__ T,
                                               float* __restrict__ ws) {
  const int b = blockIdx.y;
  const int tid = threadIdx.x;
  const int px = blockIdx.x * (TPB * 4) + tid * 4;

  const float* __restrict__ Sb = S + (size_t)b * NCH * HW;
  const float* __restrict__ Tb = T + (size_t)b * NCH * HW;
  const float* __restrict__ wm = ws + WS_MEANS + b * 68;  // wave-uniform -> SGPRs
  const float rnS0 = wm[64], rnS1 = wm[65], rnT0 = wm[66], rnT1 = wm[67];

  float4 xv[NCH];
  // ---- S ----
#pragma unroll
  for (int c = 0; c < NCH; ++c) xv[c] = *(const float4*)(Sb + (size_t)c * HW + px);
  const float4 ivS = *(const float4*)(ws + WS_INV_S + (size_t)b * HW + px);
  float4 d0 = {0, 0, 0, 0}, d1 = {0, 0, 0, 0};
#pragma unroll
  for (int c = 0; c < NCH; ++c) {
    const float w0 = wm[c], w1 = wm[16 + c];
    d0.x = fmaf(xv[c].x, w0, d0.x); d0.y = fmaf(xv[c].y, w0, d0.y);
    d0.z = fmaf(xv[c].z, w0, d0.z); d0.w = fmaf(xv[c].w, w0, d0.w);
    d1.x = fmaf(xv[c].x, w1, d1.x); d1.y = fmaf(xv[c].y, w1, d1.y);
    d1.z = fmaf(xv[c].z, w1, d1.z); d1.w = fmaf(xv[c].w, w1, d1.w);
  }
  const float pcS0 = __expf((d0.x * rnS0 - d1.x * rnS1) * ivS.x);
  const float pcS1 = __expf((d0.y * rnS0 - d1.y * rnS1) * ivS.y);
  const float pcS2 = __expf((d0.z * rnS0 - d1.z * rnS1) * ivS.z);
  const float pcS3 = __expf((d0.w * rnS0 - d1.w * rnS1) * ivS.w);

  // ---- T ----
#pragma unroll
  for (int c = 0; c < NCH; ++c) xv[c] = *(const float4*)(Tb + (size_t)c * HW + px);
  const float4 ivT = *(const float4*)(ws + WS_INV_T + (size_t)b * HW + px);
  d0 = {0, 0, 0, 0}; d1 = {0, 0, 0, 0};
#pragma unroll
  for (int c = 0; c < NCH; ++c) {
    const float w0 = wm[32 + c], w1 = wm[48 + c];
    d0.x = fmaf(xv[c].x, w0, d0.x); d0.y = fmaf(xv[c].y, w0, d0.y);
    d0.z = fmaf(xv[c].z, w0, d0.z); d0.w = fmaf(xv[c].w, w0, d0.w);
    d1.x = fmaf(xv[c].x, w1, d1.x); d1.y = fmaf(xv[c].y, w1, d1.y);
    d1.z = fmaf(xv[c].z, w1, d1.z); d1.w = fmaf(xv[c].w, w1, d1.w);
  }
  const float pcT0 = __expf((d0.x * rnT0 - d1.x * rnT1) * ivT.x);
  const float pcT1 = __expf((d0.y * rnT0 - d1.y * rnT1) * ivT.y);
  const float pcT2 = __expf((d0.z * rnT0 - d1.z * rnT1) * ivT.z);
  const float pcT3 = __expf((d0.w * rnT0 - d1.w * rnT1) * ivT.w);

  const float e0 = pcS0 - pcT0, e1 = pcS1 - pcT1;
  const float e2 = pcS2 - pcT2, e3 = pcS3 - pcT3;
  float lacc = e0 * e0 + e1 * e1 + e2 * e2 + e3 * e3;

  lacc = wave_sum(lacc);
  if ((tid & 63) == 0)
    atomicAdd(ws + WS_LOSS + b * 8 + (blockIdx.x & 7), lacc);
}

__global__ void k_final(const float* __restrict__ ws, float* __restrict__ out) {
  float s = 0.f;
  for (int i = 0; i < NBATCH * 8; ++i) s += ws[WS_LOSS + i];
  out[0] = s * (1.f / 2097152.f);  // N = 32*256*256 = 2^21, exact
}

extern "C" void kernel_launch(void* const* d_in, const int* in_sizes, int n_in,
                              void* d_out, int out_size, void* d_ws, size_t ws_size,
                              hipStream_t stream) {
  const float* S = (const float*)d_in[0];
  const float* T = (const float*)d_in[1];
  const int* tgt = (const int*)d_in[2];
  float* ws = (float*)d_ws;
  float* out = (float*)d_out;

  hipMemsetAsync(ws + WS_SMALL, 0, WS_SMALL_FLOATS * sizeof(float), stream);
  dim3 gi(HW / (TPB * 4), NBATCH, 2);
  k_inv<<<gi, TPB, 0, stream>>>(S, T, tgt, ws);
  dim3 ga(16, NBATCH, 2);
  k_acc<<<ga, TPB, 0, stream>>>(S, T, ws);
  k_prep<<<NBATCH, 64, 0, stream>>>(ws);
  dim3 g2(HW / (TPB * 4), NBATCH);
  k_pass2<<<g2, TPB, 0, stream>>>(S, T, ws);
  k_final<<<1, 1, 0, stream>>>(ws, out);
}